// Round 13
// baseline (410.688 us; speedup 1.0000x reference)
//
#include <hip/hip_runtime.h>

typedef __bf16 v8bf __attribute__((ext_vector_type(8)));
typedef __bf16 v4bf __attribute__((ext_vector_type(4)));
typedef float  v4f  __attribute__((ext_vector_type(4)));
typedef unsigned short u16;

#define LN_EPS_F 1e-5f
#define ATTN_EPS 1e-6f

static constexpr int Bsz = 32;
static constexpr int Nn  = 4096;
static constexpr int Dd  = 512;
static constexpr int Ss  = 128;
static constexpr int NSs = 8;
static constexpr int Hh  = 256;
static constexpr int MROWS = Bsz * Nn;   // 131072

__device__ __forceinline__ void load_lds16(const void* g, void* l) {
    __builtin_amdgcn_global_load_lds(
        (const __attribute__((address_space(1))) void*)g,
        (__attribute__((address_space(3))) void*)l, 16, 0, 0);
}

// ---------------------------------------------------------------------------
// Kernel 1: prep — Wkvp = bf16(W*lnw), slots init, cb[n]=lnb·W[n,:],
// Scol[n] = sum_d bf16(W*lnw)[n,d].
// ---------------------------------------------------------------------------
__global__ __launch_bounds__(256) void k_prep(const float* __restrict__ Wk, const float* __restrict__ Wv,
                                              const float* __restrict__ ln_in_w, const float* __restrict__ ln_in_b,
                                              const float* __restrict__ slots_init, const float* __restrict__ mu,
                                              const float* __restrict__ lsig,
                                              u16* __restrict__ Wkvp, float* __restrict__ cb,
                                              float* __restrict__ Scol, float* __restrict__ slots) {
    const int bid = blockIdx.x;
    const int t = threadIdx.x;
    if (bid < 512) {
        int idx = bid * 256 + t;                 // 131072 weight elems
        int n = idx >> 9, d = idx & 511;
        float w = (n < Ss) ? Wk[n * Dd + d] : Wv[(n - Ss) * Dd + d];
        w *= ln_in_w[d];
        __bf16 bv = (__bf16)w;
        Wkvp[idx] = __builtin_bit_cast(u16, bv);
    } else if (bid < 640) {
        int idx = (bid - 512) * 256 + t;         // 32768 slot elems
        int sidx = idx & (Ss - 1);
        slots[idx] = mu[sidx] + expf(lsig[sidx]) * slots_init[idx];
    } else {                                     // bids 640..647: cb + Scol
        const int wid = t >> 6, lane = t & 63;
        const int rowbase = (bid - 640) * 32 + wid * 8;
        const int d0 = lane * 8;
        float4 lw0 = *reinterpret_cast<const float4*>(ln_in_w + d0);
        float4 lw1 = *reinterpret_cast<const float4*>(ln_in_w + d0 + 4);
        float4 lb0 = *reinterpret_cast<const float4*>(ln_in_b + d0);
        float4 lb1 = *reinterpret_cast<const float4*>(ln_in_b + d0 + 4);
        for (int rr = 0; rr < 8; ++rr) {
            int row = rowbase + rr;
            const float* wrow = (row < Ss) ? (Wk + (size_t)row * Dd)
                                           : (Wv + (size_t)(row - Ss) * Dd);
            float4 w0 = *reinterpret_cast<const float4*>(wrow + d0);
            float4 w1 = *reinterpret_cast<const float4*>(wrow + d0 + 4);
            float accb = lb0.x*w0.x + lb0.y*w0.y + lb0.z*w0.z + lb0.w*w0.w
                       + lb1.x*w1.x + lb1.y*w1.y + lb1.z*w1.z + lb1.w*w1.w;
            float accs = (float)(__bf16)(w0.x*lw0.x) + (float)(__bf16)(w0.y*lw0.y)
                       + (float)(__bf16)(w0.z*lw0.z) + (float)(__bf16)(w0.w*lw0.w)
                       + (float)(__bf16)(w1.x*lw1.x) + (float)(__bf16)(w1.y*lw1.y)
                       + (float)(__bf16)(w1.z*lw1.z) + (float)(__bf16)(w1.w*lw1.w);
#pragma unroll
            for (int off = 32; off > 0; off >>= 1) {
                accb += __shfl_xor(accb, off);
                accs += __shfl_xor(accs, off);
            }
            if (lane == 0) { cb[row] = accb; Scol[row] = accs; }
        }
    }
}

// ---------------------------------------------------------------------------
// Kernel 2: fused LN + K/V GEMM — R3 pipeline, BK=32, now min 4 waves/EU
// (VGPR cap 128; acc=64 + staging ~50 should fit, LDS 37.5KB x4 = 150KB).
// B: global_load_lds dbuf, source pre-swizzled, counted vmcnt(6).
// A: reg-staged fp32->bf16 + stats, 1-step prefetch.
// Epilogue: out = rstd*(acc - mean*Scol) + cb.
// ---------------------------------------------------------------------------
__global__ __launch_bounds__(256, 4) void k_kvgemm(const float* __restrict__ X,
                                                   const u16* __restrict__ Wkvp,
                                                   const float* __restrict__ cb,
                                                   const float* __restrict__ Scol,
                                                   u16* __restrict__ kv) {
    __shared__ __bf16 As[64][40];        // 5 KB, 80B row stride (2-way banks = free)
    __shared__ __bf16 Bs[2][256 * 32];   // 32 KB
    __shared__ float2 stats_sh[64];
    const int t    = threadIdx.x;
    const int lane = t & 63;
    const int wid  = t >> 6;
    const size_t m0 = (size_t)blockIdx.x * 64;

    const int ar  = t >> 2;              // A row (0..63), 4 threads/row
    const int ac0 = (t & 3) * 8;         // 8-elem slice base within 32-col step
    const float* xrow = X + (m0 + ar) * Dd;

    // B staging: wave wid rows wid*64..+63; 4 instrs x 16 rows x 64B.
    // lane -> row lane>>2, phys slot lane&3; src slot = (lane&3)^((lane>>3)&3).
    const u16* bsrc = Wkvp + (size_t)(wid * 64 + (lane >> 2)) * Dd
                           + (size_t)(((lane & 3) ^ ((lane >> 3) & 3)) * 8);

    const v4f vzero = {0.f, 0.f, 0.f, 0.f};
    v4f acc[4][4];
#pragma unroll
    for (int i = 0; i < 4; ++i)
#pragma unroll
        for (int j = 0; j < 4; ++j) acc[i][j] = vzero;

    const int g  = lane >> 4;
    const int lr = lane & 15;
    float s1 = 0.f, s2 = 0.f;

#define STAGE_B(buf, kb)                                                        \
    {                                                                           \
        _Pragma("unroll")                                                       \
        for (int i = 0; i < 4; ++i)                                             \
            load_lds16(bsrc + (size_t)i * 16 * Dd + (kb) * 32,                  \
                       &Bs[buf][(wid * 64 + i * 16) * 32]);                     \
    }

    // prologue: A(0) to regs first, then B(0), B(1)
    float4 a_pre[2];
    a_pre[0] = *reinterpret_cast<const float4*>(xrow + ac0);
    a_pre[1] = *reinterpret_cast<const float4*>(xrow + ac0 + 4);
    STAGE_B(0, 0);
    STAGE_B(1, 1);

    const int cob = (g ^ ((lr >> 1) & 3)) * 8;   // swizzled B read slot

#pragma unroll
    for (int kb = 0; kb < 16; ++kb) {
        // (1) cvt + stats + ds_write A(kb)
        {
            float4 lo = a_pre[0], hi = a_pre[1];
            s1 += lo.x + lo.y + lo.z + lo.w + hi.x + hi.y + hi.z + hi.w;
            s2 += lo.x*lo.x + lo.y*lo.y + lo.z*lo.z + lo.w*lo.w
                + hi.x*hi.x + hi.y*hi.y + hi.z*hi.z + hi.w*hi.w;
            v4bf w0, w1;
            w0[0] = (__bf16)lo.x; w0[1] = (__bf16)lo.y; w0[2] = (__bf16)lo.z; w0[3] = (__bf16)lo.w;
            w1[0] = (__bf16)hi.x; w1[1] = (__bf16)hi.y; w1[2] = (__bf16)hi.z; w1[3] = (__bf16)hi.w;
            *reinterpret_cast<v4bf*>(&As[ar][ac0])     = w0;
            *reinterpret_cast<v4bf*>(&As[ar][ac0 + 4]) = w1;
        }
        // (2) prefetch A(kb+1) to regs (flies across the barrier)
        if (kb < 15) {
            a_pre[0] = *reinterpret_cast<const float4*>(xrow + (kb + 1) * 32 + ac0);
            a_pre[1] = *reinterpret_cast<const float4*>(xrow + (kb + 1) * 32 + ac0 + 4);
        }
        // (3) wait B(kb) landed (6 newer: A(kb+1)[2]+B(kb+1)[4]); A writes visible
        if (kb < 15)
            asm volatile("s_waitcnt vmcnt(6) lgkmcnt(0)\ns_barrier" ::: "memory");
        else
            asm volatile("s_waitcnt vmcnt(0) lgkmcnt(0)\ns_barrier" ::: "memory");
        // (4) compute: 16 MFMA (4x4), BK=32 = one K-slice
        {
            const __bf16* bbase = &Bs[kb & 1][0];
            v8bf a[4], bfr[4];
#pragma unroll
            for (int mi = 0; mi < 4; ++mi)
                a[mi] = *reinterpret_cast<const v8bf*>(&As[mi * 16 + lr][g * 8]);
#pragma unroll
            for (int ni = 0; ni < 4; ++ni) {
                int r = wid * 64 + ni * 16 + lr;
                bfr[ni] = *reinterpret_cast<const v8bf*>(&bbase[r * 32 + cob]);
            }
#pragma unroll
            for (int mi = 0; mi < 4; ++mi)
#pragma unroll
                for (int ni = 0; ni < 4; ++ni)
                    acc[mi][ni] = __builtin_amdgcn_mfma_f32_16x16x32_bf16(a[mi], bfr[ni], acc[mi][ni], 0, 0, 0);
        }
        // (5) protect As / Bs[cur] before next overwrite
        asm volatile("s_barrier" ::: "memory");
        // (6) issue B(kb+2) into the buffer just consumed
        if (kb < 14) STAGE_B(kb & 1, kb + 2);
    }
#undef STAGE_B
    // ---- stats reduce (4 threads share row ar via lane bits 0-1)
    s1 += __shfl_xor(s1, 1); s1 += __shfl_xor(s1, 2);
    s2 += __shfl_xor(s2, 1); s2 += __shfl_xor(s2, 2);
    if ((t & 3) == 0) {
        float m = s1 * (1.f / Dd);
        float v = s2 * (1.f / Dd) - m * m;
        stats_sh[ar] = make_float2(m, rsqrtf(v + LN_EPS_F));
    }
    __syncthreads();
    // ---- epilogue: out = rstd*(acc - m*Scol) + cb
    float Sn[4], cbv[4];
#pragma unroll
    for (int ni = 0; ni < 4; ++ni) {
        int ng = wid * 64 + ni * 16 + lr;
        Sn[ni]  = Scol[ng];
        cbv[ni] = cb[ng];
    }
#pragma unroll
    for (int mi = 0; mi < 4; ++mi)
#pragma unroll
        for (int j = 0; j < 4; ++j) {
            float2 st = stats_sh[mi * 16 + g * 4 + j];
            size_t mg = m0 + mi * 16 + g * 4 + j;
#pragma unroll
            for (int ni = 0; ni < 4; ++ni) {
                int ng = wid * 64 + ni * 16 + lr;
                float val = st.y * (acc[mi][ni][j] - st.x * Sn[ni]) + cbv[ni];
                __bf16 bv = (__bf16)val;
                kv[mg * 256 + ng] = __builtin_bit_cast(u16, bv);
            }
        }
}

// ---------------------------------------------------------------------------
// Kernel 3: initial q = LN_slot(slots) @ Wq^T * scale.  One block per (b,m).
// ---------------------------------------------------------------------------
__global__ __launch_bounds__(128) void k_q(const float* __restrict__ slots,
                                           const float* __restrict__ lnw, const float* __restrict__ lnb,
                                           const float* __restrict__ Wq, float* __restrict__ q) {
    __shared__ float xs[128];
    __shared__ float red[4];
    const int t = threadIdx.x;
    const int bm = blockIdx.x;
    float x = slots[bm * 128 + t];
    float s = x, s2 = x * x;
#pragma unroll
    for (int off = 32; off > 0; off >>= 1) { s += __shfl_xor(s, off); s2 += __shfl_xor(s2, off); }
    const int wid = t >> 6, lane = t & 63;
    if (lane == 0) { red[wid * 2] = s; red[wid * 2 + 1] = s2; }
    __syncthreads();
    float S1 = red[0] + red[2], S2 = red[1] + red[3];
    float m = S1 * (1.f / 128.f);
    float rstd = rsqrtf(S2 * (1.f / 128.f) - m * m + LN_EPS_F);
    xs[t] = (x - m) * rstd * lnw[t] + lnb[t];
    __syncthreads();
    const float* wr = Wq + (size_t)t * 128;
    float acc = 0.f;
#pragma unroll 8
    for (int d = 0; d < 128; d += 4) {
        float4 w = *reinterpret_cast<const float4*>(wr + d);
        acc += w.x * xs[d] + w.y * xs[d + 1] + w.z * xs[d + 2] + w.w * xs[d + 3];
    }
    q[bm * 128 + t] = acc * 0.08838834764831845f;
}

// ---------------------------------------------------------------------------
// Kernel 4: fused attn logits + softmax + partial updates per (b,chunk).
// ---------------------------------------------------------------------------
__global__ __launch_bounds__(256) void k_attnupd(const u16* __restrict__ kv, const float* __restrict__ q,
                                                 float* __restrict__ upd_part, float* __restrict__ colsum_part) {
    __shared__ float qs[8 * 128];
    __shared__ float at[128][8];
    __shared__ __bf16 vt[128][128];
    __shared__ float colpart[4][8];
    const int b  = blockIdx.y;
    const int ch = blockIdx.x;
    const int t  = threadIdx.x;
    const int lane = t & 63, wv = t >> 6;
    *reinterpret_cast<float4*>(&qs[t * 4]) = *reinterpret_cast<const float4*>(&q[b * 1024 + t * 4]);
    __syncthreads();
    {
        const int rsub = lane >> 4;
        const int csub = (lane & 15) * 8;
#pragma unroll
        for (int p = 0; p < 8; ++p) {
            int row = wv * 32 + p * 4;
            const u16* src = kv + ((size_t)(b * Nn + ch * 128 + row + rsub)) * 256 + 128 + csub;
            load_lds16(src, &vt[row][0]);
        }
    }
    const int nl   = t >> 1;
    const int half = t & 1;
    const u16* krow = kv + ((size_t)(b * Nn + ch * 128 + nl)) * 256 + half * 64;
    float acc[8] = {0.f, 0.f, 0.f, 0.f, 0.f, 0.f, 0.f, 0.f};
#pragma unroll
    for (int c = 0; c < 8; ++c) {
        v8bf kvv = *reinterpret_cast<const v8bf*>(krow + c * 8);
        float kf[8];
#pragma unroll
        for (int j = 0; j < 8; ++j) kf[j] = (float)kvv[j];
#pragma unroll
        for (int m = 0; m < 8; ++m) {
            const float* qrow = &qs[m * 128 + half * 64 + c * 8];
            float aa = 0.f;
#pragma unroll
            for (int j = 0; j < 8; ++j) aa += kf[j] * qrow[j];
            acc[m] += aa;
        }
    }
#pragma unroll
    for (int m = 0; m < 8; ++m) acc[m] += __shfl_xor(acc[m], 1);
    float mx = acc[0];
#pragma unroll
    for (int m = 1; m < 8; ++m) mx = fmaxf(mx, acc[m]);
    float e[8]; float ssum = 0.f;
#pragma unroll
    for (int m = 0; m < 8; ++m) { e[m] = __expf(acc[m] - mx); ssum += e[m]; }
    float inv = 1.0f / ssum;
    float a8[8];
#pragma unroll
    for (int m = 0; m < 8; ++m) a8[m] = e[m] * inv + ATTN_EPS;
    *reinterpret_cast<float4*>(&at[nl][half * 4]) =
        make_float4(a8[half * 4], a8[half * 4 + 1], a8[half * 4 + 2], a8[half * 4 + 3]);
#pragma unroll
    for (int m = 0; m < 8; ++m) {
        float v = a8[m];
#pragma unroll
        for (int off = 32; off > 0; off >>= 1) v += __shfl_xor(v, off);
        if (lane == 0) colpart[wv][m] = v * 0.5f;
    }
    __syncthreads();
    const int m2 = t >> 5;
    const int s0 = (t & 31) * 4;
    float a0 = 0.f, a1 = 0.f, a2 = 0.f, a3 = 0.f;
#pragma unroll 4
    for (int n = 0; n < 128; ++n) {
        float a = at[n][m2];
        v4bf vvv = *reinterpret_cast<const v4bf*>(&vt[n][s0]);
        a0 += a * (float)vvv[0];
        a1 += a * (float)vvv[1];
        a2 += a * (float)vvv[2];
        a3 += a * (float)vvv[3];
    }
    *reinterpret_cast<float4*>(upd_part + ((size_t)(b * 32 + ch) * 8 + m2) * 128 + s0) =
        make_float4(a0, a1, a2, a3);
    if (t < 8)
        colsum_part[(b * 32 + ch) * 8 + t] =
            colpart[0][t] + colpart[1][t] + colpart[2][t] + colpart[3][t];
}

// ---------------------------------------------------------------------------
// Kernel 5: reduce partials, GRU, LN, MLP -> new slots; next-iter q.
// 256 threads: (tid, half) split-K halves the serial fma chains; 4 waves.
// ---------------------------------------------------------------------------
__global__ __launch_bounds__(256) void k_finishq(const float* __restrict__ upd_part,
                                                 const float* __restrict__ colsum_part,
                                                 const float* __restrict__ slots_in,
                                                 const float* __restrict__ Wih, const float* __restrict__ Whh,
                                                 const float* __restrict__ bih, const float* __restrict__ bhh,
                                                 const float* __restrict__ lnw, const float* __restrict__ lnb,
                                                 const float* __restrict__ W1, const float* __restrict__ b1,
                                                 const float* __restrict__ W2, const float* __restrict__ b2,
                                                 const float* __restrict__ lnsw, const float* __restrict__ lnsb,
                                                 const float* __restrict__ Wq,
                                                 float* __restrict__ slots_out, float* __restrict__ qout) {
    __shared__ float us[128], sp[128], hnorm[128], qsrc[128], act[256];
    __shared__ float upart[2][128];
    __shared__ float gpart[2][6][128];
    __shared__ float p2[2][128];
    __shared__ float qpart[2][128];
    __shared__ float red[4];
    __shared__ float csum_sh;
    const int t   = threadIdx.x;
    const int tid = t & 127, half = t >> 7;
    const int bm  = blockIdx.x;
    const int b = bm >> 3, m = bm & 7;
    if (t < 64) {
        float v = (t < 32) ? colsum_part[(b * 32 + t) * 8 + m] : 0.f;
#pragma unroll
        for (int off = 32; off > 0; off >>= 1) v += __shfl_xor(v, off);
        if (t == 0) csum_sh = v;
    }
    float u = 0.f;
#pragma unroll 4
    for (int chk = half * 16; chk < half * 16 + 16; ++chk)
        u += upd_part[((size_t)(b * 32 + chk) * 8 + m) * 128 + tid];
    upart[half][tid] = u;
    if (half == 0) sp[tid] = slots_in[bm * 128 + tid];
    __syncthreads();
    if (half == 0) us[tid] = (upart[0][tid] + upart[1][tid]) * (1.f / csum_sh);
    __syncthreads();
    // ---- GRU partial dots (split-K over halves)
    {
        const int d0g = half * 64;
        float a_r = 0.f, a_z = 0.f, a_n = 0.f, b_r = 0.f, b_z = 0.f, b_n = 0.f;
        const float* Wr = Wih + (size_t)tid * 128 + d0g;
        const float* Wz = Wih + (size_t)(128 + tid) * 128 + d0g;
        const float* Wn = Wih + (size_t)(256 + tid) * 128 + d0g;
        const float* Vr = Whh + (size_t)tid * 128 + d0g;
        const float* Vz = Whh + (size_t)(128 + tid) * 128 + d0g;
        const float* Vn = Whh + (size_t)(256 + tid) * 128 + d0g;
#pragma unroll 4
        for (int d = 0; d < 64; d += 4) {
            float u0 = us[d0g + d], u1 = us[d0g + d + 1], u2 = us[d0g + d + 2], u3 = us[d0g + d + 3];
            float p0 = sp[d0g + d], p1 = sp[d0g + d + 1], p2_ = sp[d0g + d + 2], p3 = sp[d0g + d + 3];
            float4 w;
            w = *reinterpret_cast<const float4*>(Wr + d); a_r += w.x*u0 + w.y*u1 + w.z*u2 + w.w*u3;
            w = *reinterpret_cast<const float4*>(Wz + d); a_z += w.x*u0 + w.y*u1 + w.z*u2 + w.w*u3;
            w = *reinterpret_cast<const float4*>(Wn + d); a_n += w.x*u0 + w.y*u1 + w.z*u2 + w.w*u3;
            w = *reinterpret_cast<const float4*>(Vr + d); b_r += w.x*p0 + w.y*p1 + w.z*p2_ + w.w*p3;
            w = *reinterpret_cast<const float4*>(Vz + d); b_z += w.x*p0 + w.y*p1 + w.z*p2_ + w.w*p3;
            w = *reinterpret_cast<const float4*>(Vn + d); b_n += w.x*p0 + w.y*p1 + w.z*p2_ + w.w*p3;
        }
        gpart[half][0][tid] = a_r; gpart[half][1][tid] = a_z; gpart[half][2][tid] = a_n;
        gpart[half][3][tid] = b_r; gpart[half][4][tid] = b_z; gpart[half][5][tid] = b_n;
    }
    __syncthreads();
    float gir = bih[tid]       + gpart[0][0][tid] + gpart[1][0][tid];
    float giz = bih[128 + tid] + gpart[0][1][tid] + gpart[1][1][tid];
    float gin = bih[256 + tid] + gpart[0][2][tid] + gpart[1][2][tid];
    float ghr = bhh[tid]       + gpart[0][3][tid] + gpart[1][3][tid];
    float ghz = bhh[128 + tid] + gpart[0][4][tid] + gpart[1][4][tid];
    float ghn = bhh[256 + tid] + gpart[0][5][tid] + gpart[1][5][tid];
    float h0 = sp[tid];
    float r  = 1.f / (1.f + __expf(-(gir + ghr)));
    float z  = 1.f / (1.f + __expf(-(giz + ghz)));
    float nn = tanhf(gin + r * ghn);
    float h  = (1.f - z) * nn + z * h0;
    // ---- LN(h) (reduce on half 0: waves 0-1)
    if (half == 0) {
        float s = h, s2 = h * h;
#pragma unroll
        for (int off = 32; off > 0; off >>= 1) { s += __shfl_xor(s, off); s2 += __shfl_xor(s2, off); }
        if ((t & 63) == 0) { red[(tid >> 6) * 2] = s; red[(tid >> 6) * 2 + 1] = s2; }
    }
    __syncthreads();
    {
        float S1 = red[0] + red[2], S2 = red[1] + red[3];
        float mean = S1 * (1.f / Ss);
        float rstd = rsqrtf(S2 * (1.f / Ss) - mean * mean + LN_EPS_F);
        if (half == 0) hnorm[tid] = (h - mean) * rstd * lnw[tid] + lnb[tid];
    }
    __syncthreads();
    // ---- MLP1: each of 256 threads one output
    {
        float a = b1[t];
        const float* w1r = W1 + (size_t)t * 128;
#pragma unroll 4
        for (int d = 0; d < 128; d += 4) {
            float4 w = *reinterpret_cast<const float4*>(w1r + d);
            a += w.x * hnorm[d] + w.y * hnorm[d + 1] + w.z * hnorm[d + 2] + w.w * hnorm[d + 3];
        }
        act[t] = fmaxf(a, 0.f);
    }
    __syncthreads();
    // ---- MLP2 split-K
    {
        float o = 0.f;
        const int j0 = half * 128;
        const float* w2r = W2 + (size_t)tid * 256 + j0;
#pragma unroll 4
        for (int j = 0; j < 128; j += 4) {
            float4 w = *reinterpret_cast<const float4*>(w2r + j);
            o += w.x * act[j0 + j] + w.y * act[j0 + j + 1] + w.z * act[j0 + j + 2] + w.w * act[j0 + j + 3];
        }
        p2[half][tid] = o;
    }
    __syncthreads();
    float snew = h + b2[tid] + p2[0][tid] + p2[1][tid];
    if (half == 0) slots_out[bm * 128 + tid] = snew;
    // ---- next-iter q
    if (half == 0) {
        float s = snew, s2 = snew * snew;
#pragma unroll
        for (int off = 32; off > 0; off >>= 1) { s += __shfl_xor(s, off); s2 += __shfl_xor(s2, off); }
        if ((t & 63) == 0) { red[(tid >> 6) * 2] = s; red[(tid >> 6) * 2 + 1] = s2; }
    }
    __syncthreads();
    {
        float T1 = red[0] + red[2], T2 = red[1] + red[3];
        float m2 = T1 * (1.f / Ss);
        float rstd2 = rsqrtf(T2 * (1.f / Ss) - m2 * m2 + LN_EPS_F);
        if (half == 0) qsrc[tid] = (snew - m2) * rstd2 * lnsw[tid] + lnsb[tid];
    }
    __syncthreads();
    {
        float qa = 0.f;
        const int d0g = half * 64;
        const float* wr = Wq + (size_t)tid * 128 + d0g;
#pragma unroll 4
        for (int d = 0; d < 64; d += 4) {
            float4 w = *reinterpret_cast<const float4*>(wr + d);
            qa += w.x * qsrc[d0g + d] + w.y * qsrc[d0g + d + 1] + w.z * qsrc[d0g + d + 2] + w.w * qsrc[d0g + d + 3];
        }
        qpart[half][tid] = qa;
    }
    __syncthreads();
    if (half == 0)
        qout[bm * 128 + tid] = (qpart[0][tid] + qpart[1][tid]) * 0.08838834764831845f;
}

// ---------------------------------------------------------------------------
extern "C" void kernel_launch(void* const* d_in, const int* in_sizes, int n_in,
                              void* d_out, int out_size, void* d_ws, size_t ws_size,
                              hipStream_t stream) {
    const float* X          = (const float*)d_in[0];
    const float* slots_init = (const float*)d_in[1];
    const float* ln_in_w    = (const float*)d_in[2];
    const float* ln_in_b    = (const float*)d_in[3];
    const float* ln_slot_w  = (const float*)d_in[4];
    const float* ln_slot_b  = (const float*)d_in[5];
    const float* ln_mlp_w   = (const float*)d_in[6];
    const float* ln_mlp_b   = (const float*)d_in[7];
    const float* Wq         = (const float*)d_in[8];
    const float* Wk         = (const float*)d_in[9];
    const float* Wv         = (const float*)d_in[10];
    const float* gWih       = (const float*)d_in[11];
    const float* gWhh       = (const float*)d_in[12];
    const float* gbih       = (const float*)d_in[13];
    const float* gbhh       = (const float*)d_in[14];
    const float* W1         = (const float*)d_in[15];
    const float* b1         = (const float*)d_in[16];
    const float* W2         = (const float*)d_in[17];
    const float* b2         = (const float*)d_in[18];
    const float* mu         = (const float*)d_in[19];
    const float* lsig       = (const float*)d_in[20];

    char* p = (char*)d_ws;
    u16*    Wkvp        = (u16*)p;    p += (size_t)256 * 512 * sizeof(u16);           // 256 KB
    float*  cb          = (float*)p;  p += 256 * sizeof(float);
    float*  Scol        = (float*)p;  p += 256 * sizeof(float);
    float*  slots       = (float*)p;  p += 32 * 8 * 128 * sizeof(float);              // 128 KB
    float*  qbuf        = (float*)p;  p += 32 * 8 * 128 * sizeof(float);              // 128 KB
    float*  colsum_part = (float*)p;  p += 32 * 32 * 8 * sizeof(float);               // 32 KB
    float*  upd_part    = (float*)p;  p += (size_t)32 * 32 * 8 * 128 * sizeof(float); // 4 MB
    u16*    kv          = (u16*)p;    p += (size_t)MROWS * 256 * sizeof(u16);         // 67 MB

    k_prep<<<648, 256, 0, stream>>>(Wk, Wv, ln_in_w, ln_in_b, slots_init, mu, lsig,
                                    Wkvp, cb, Scol, slots);
    k_kvgemm<<<MROWS / 64, 256, 0, stream>>>(X, Wkvp, cb, Scol, kv);
    k_q<<<256, 128, 0, stream>>>(slots, ln_slot_w, ln_slot_b, Wq, qbuf);

    for (int it = 0; it < 3; ++it) {
        k_attnupd<<<dim3(32, 32), 256, 0, stream>>>(kv, qbuf, upd_part, colsum_part);
        k_finishq<<<256, 256, 0, stream>>>(upd_part, colsum_part, slots,
                                           gWih, gWhh, gbih, gbhh,
                                           ln_mlp_w, ln_mlp_b, W1, b1, W2, b2,
                                           ln_slot_w, ln_slot_b, Wq,
                                           (it == 2) ? (float*)d_out : slots, qbuf);
    }
}

// Round 14
// 299.829 us; speedup vs baseline: 1.3697x; 1.3697x over previous
//
#include <hip/hip_runtime.h>

typedef __bf16 v8bf __attribute__((ext_vector_type(8)));
typedef __bf16 v4bf __attribute__((ext_vector_type(4)));
typedef float  v4f  __attribute__((ext_vector_type(4)));
typedef unsigned short u16;

#define LN_EPS_F 1e-5f
#define ATTN_EPS 1e-6f

static constexpr int Bsz = 32;
static constexpr int Nn  = 4096;
static constexpr int Dd  = 512;
static constexpr int Ss  = 128;
static constexpr int NSs = 8;
static constexpr int Hh  = 256;
static constexpr int MROWS = Bsz * Nn;   // 131072

__device__ __forceinline__ void load_lds16(const void* g, void* l) {
    __builtin_amdgcn_global_load_lds(
        (const __attribute__((address_space(1))) void*)g,
        (__attribute__((address_space(3))) void*)l, 16, 0, 0);
}

// ---------------------------------------------------------------------------
// Kernel 1: prep — Wkvp = bf16(W*lnw), slots init, cb[n]=lnb·W[n,:],
// Scol[n] = sum_d bf16(W*lnw)[n,d].
// ---------------------------------------------------------------------------
__global__ __launch_bounds__(256) void k_prep(const float* __restrict__ Wk, const float* __restrict__ Wv,
                                              const float* __restrict__ ln_in_w, const float* __restrict__ ln_in_b,
                                              const float* __restrict__ slots_init, const float* __restrict__ mu,
                                              const float* __restrict__ lsig,
                                              u16* __restrict__ Wkvp, float* __restrict__ cb,
                                              float* __restrict__ Scol, float* __restrict__ slots) {
    const int bid = blockIdx.x;
    const int t = threadIdx.x;
    if (bid < 512) {
        int idx = bid * 256 + t;                 // 131072 weight elems
        int n = idx >> 9, d = idx & 511;
        float w = (n < Ss) ? Wk[n * Dd + d] : Wv[(n - Ss) * Dd + d];
        w *= ln_in_w[d];
        __bf16 bv = (__bf16)w;
        Wkvp[idx] = __builtin_bit_cast(u16, bv);
    } else if (bid < 640) {
        int idx = (bid - 512) * 256 + t;         // 32768 slot elems
        int sidx = idx & (Ss - 1);
        slots[idx] = mu[sidx] + expf(lsig[sidx]) * slots_init[idx];
    } else {                                     // bids 640..647: cb + Scol
        const int wid = t >> 6, lane = t & 63;
        const int rowbase = (bid - 640) * 32 + wid * 8;
        const int d0 = lane * 8;
        float4 lw0 = *reinterpret_cast<const float4*>(ln_in_w + d0);
        float4 lw1 = *reinterpret_cast<const float4*>(ln_in_w + d0 + 4);
        float4 lb0 = *reinterpret_cast<const float4*>(ln_in_b + d0);
        float4 lb1 = *reinterpret_cast<const float4*>(ln_in_b + d0 + 4);
        for (int rr = 0; rr < 8; ++rr) {
            int row = rowbase + rr;
            const float* wrow = (row < Ss) ? (Wk + (size_t)row * Dd)
                                           : (Wv + (size_t)(row - Ss) * Dd);
            float4 w0 = *reinterpret_cast<const float4*>(wrow + d0);
            float4 w1 = *reinterpret_cast<const float4*>(wrow + d0 + 4);
            float accb = lb0.x*w0.x + lb0.y*w0.y + lb0.z*w0.z + lb0.w*w0.w
                       + lb1.x*w1.x + lb1.y*w1.y + lb1.z*w1.z + lb1.w*w1.w;
            float accs = (float)(__bf16)(w0.x*lw0.x) + (float)(__bf16)(w0.y*lw0.y)
                       + (float)(__bf16)(w0.z*lw0.z) + (float)(__bf16)(w0.w*lw0.w)
                       + (float)(__bf16)(w1.x*lw1.x) + (float)(__bf16)(w1.y*lw1.y)
                       + (float)(__bf16)(w1.z*lw1.z) + (float)(__bf16)(w1.w*lw1.w);
#pragma unroll
            for (int off = 32; off > 0; off >>= 1) {
                accb += __shfl_xor(accb, off);
                accs += __shfl_xor(accs, off);
            }
            if (lane == 0) { cb[row] = accb; Scol[row] = accs; }
        }
    }
}

// ---------------------------------------------------------------------------
// Kernel 2: fused LN + K/V GEMM — R3 pipeline with BK=32, min 3 waves/EU
// (R12-verified best: ~148us, VGPR~110, no spills.  (256,4) forced VGPR=64
// -> 390MB spill traffic, 241us.  R3's BK=64 at 1-2 blocks/CU: 155us.)
// B: global_load_lds dbuf, source pre-swizzled, counted vmcnt(6).
// A: reg-staged fp32->bf16 + stats, 1-step prefetch.
// Epilogue: out = rstd*(acc - mean*Scol) + cb.
// ---------------------------------------------------------------------------
__global__ __launch_bounds__(256, 3) void k_kvgemm(const float* __restrict__ X,
                                                   const u16* __restrict__ Wkvp,
                                                   const float* __restrict__ cb,
                                                   const float* __restrict__ Scol,
                                                   u16* __restrict__ kv) {
    __shared__ __bf16 As[64][40];        // 5 KB, 80B row stride (2-way banks = free)
    __shared__ __bf16 Bs[2][256 * 32];   // 32 KB
    __shared__ float2 stats_sh[64];
    const int t    = threadIdx.x;
    const int lane = t & 63;
    const int wid  = t >> 6;
    const size_t m0 = (size_t)blockIdx.x * 64;

    const int ar  = t >> 2;              // A row (0..63), 4 threads/row
    const int ac0 = (t & 3) * 8;         // 8-elem slice base within 32-col step
    const float* xrow = X + (m0 + ar) * Dd;

    // B staging: wave wid rows wid*64..+63; 4 instrs x 16 rows x 64B.
    // lane -> row lane>>2, phys slot lane&3; src slot = (lane&3)^((lane>>3)&3).
    const u16* bsrc = Wkvp + (size_t)(wid * 64 + (lane >> 2)) * Dd
                           + (size_t)(((lane & 3) ^ ((lane >> 3) & 3)) * 8);

    const v4f vzero = {0.f, 0.f, 0.f, 0.f};
    v4f acc[4][4];
#pragma unroll
    for (int i = 0; i < 4; ++i)
#pragma unroll
        for (int j = 0; j < 4; ++j) acc[i][j] = vzero;

    const int g  = lane >> 4;
    const int lr = lane & 15;
    float s1 = 0.f, s2 = 0.f;

#define STAGE_B(buf, kb)                                                        \
    {                                                                           \
        _Pragma("unroll")                                                       \
        for (int i = 0; i < 4; ++i)                                             \
            load_lds16(bsrc + (size_t)i * 16 * Dd + (kb) * 32,                  \
                       &Bs[buf][(wid * 64 + i * 16) * 32]);                     \
    }

    // prologue: A(0) to regs first, then B(0), B(1)
    float4 a_pre[2];
    a_pre[0] = *reinterpret_cast<const float4*>(xrow + ac0);
    a_pre[1] = *reinterpret_cast<const float4*>(xrow + ac0 + 4);
    STAGE_B(0, 0);
    STAGE_B(1, 1);

    const int cob = (g ^ ((lr >> 1) & 3)) * 8;   // swizzled B read slot

#pragma unroll
    for (int kb = 0; kb < 16; ++kb) {
        // (1) cvt + stats + ds_write A(kb)
        {
            float4 lo = a_pre[0], hi = a_pre[1];
            s1 += lo.x + lo.y + lo.z + lo.w + hi.x + hi.y + hi.z + hi.w;
            s2 += lo.x*lo.x + lo.y*lo.y + lo.z*lo.z + lo.w*lo.w
                + hi.x*hi.x + hi.y*hi.y + hi.z*hi.z + hi.w*hi.w;
            v4bf w0, w1;
            w0[0] = (__bf16)lo.x; w0[1] = (__bf16)lo.y; w0[2] = (__bf16)lo.z; w0[3] = (__bf16)lo.w;
            w1[0] = (__bf16)hi.x; w1[1] = (__bf16)hi.y; w1[2] = (__bf16)hi.z; w1[3] = (__bf16)hi.w;
            *reinterpret_cast<v4bf*>(&As[ar][ac0])     = w0;
            *reinterpret_cast<v4bf*>(&As[ar][ac0 + 4]) = w1;
        }
        // (2) prefetch A(kb+1) to regs (flies across the barrier)
        if (kb < 15) {
            a_pre[0] = *reinterpret_cast<const float4*>(xrow + (kb + 1) * 32 + ac0);
            a_pre[1] = *reinterpret_cast<const float4*>(xrow + (kb + 1) * 32 + ac0 + 4);
        }
        // (3) wait B(kb) landed (6 newer: A(kb+1)[2]+B(kb+1)[4]); A writes visible
        if (kb < 15)
            asm volatile("s_waitcnt vmcnt(6) lgkmcnt(0)\ns_barrier" ::: "memory");
        else
            asm volatile("s_waitcnt vmcnt(0) lgkmcnt(0)\ns_barrier" ::: "memory");
        // (4) compute: 16 MFMA (4x4), BK=32 = one K-slice
        {
            const __bf16* bbase = &Bs[kb & 1][0];
            v8bf a[4], bfr[4];
#pragma unroll
            for (int mi = 0; mi < 4; ++mi)
                a[mi] = *reinterpret_cast<const v8bf*>(&As[mi * 16 + lr][g * 8]);
#pragma unroll
            for (int ni = 0; ni < 4; ++ni) {
                int r = wid * 64 + ni * 16 + lr;
                bfr[ni] = *reinterpret_cast<const v8bf*>(&bbase[r * 32 + cob]);
            }
#pragma unroll
            for (int mi = 0; mi < 4; ++mi)
#pragma unroll
                for (int ni = 0; ni < 4; ++ni)
                    acc[mi][ni] = __builtin_amdgcn_mfma_f32_16x16x32_bf16(a[mi], bfr[ni], acc[mi][ni], 0, 0, 0);
        }
        // (5) protect As / Bs[cur] before next overwrite
        asm volatile("s_barrier" ::: "memory");
        // (6) issue B(kb+2) into the buffer just consumed
        if (kb < 14) STAGE_B(kb & 1, kb + 2);
    }
#undef STAGE_B
    // ---- stats reduce (4 threads share row ar via lane bits 0-1)
    s1 += __shfl_xor(s1, 1); s1 += __shfl_xor(s1, 2);
    s2 += __shfl_xor(s2, 1); s2 += __shfl_xor(s2, 2);
    if ((t & 3) == 0) {
        float m = s1 * (1.f / Dd);
        float v = s2 * (1.f / Dd) - m * m;
        stats_sh[ar] = make_float2(m, rsqrtf(v + LN_EPS_F));
    }
    __syncthreads();
    // ---- epilogue: out = rstd*(acc - m*Scol) + cb
    float Sn[4], cbv[4];
#pragma unroll
    for (int ni = 0; ni < 4; ++ni) {
        int ng = wid * 64 + ni * 16 + lr;
        Sn[ni]  = Scol[ng];
        cbv[ni] = cb[ng];
    }
#pragma unroll
    for (int mi = 0; mi < 4; ++mi)
#pragma unroll
        for (int j = 0; j < 4; ++j) {
            float2 st = stats_sh[mi * 16 + g * 4 + j];
            size_t mg = m0 + mi * 16 + g * 4 + j;
#pragma unroll
            for (int ni = 0; ni < 4; ++ni) {
                int ng = wid * 64 + ni * 16 + lr;
                float val = st.y * (acc[mi][ni][j] - st.x * Sn[ni]) + cbv[ni];
                __bf16 bv = (__bf16)val;
                kv[mg * 256 + ng] = __builtin_bit_cast(u16, bv);
            }
        }
}

// ---------------------------------------------------------------------------
// Kernel 3: initial q = LN_slot(slots) @ Wq^T * scale.  One block per (b,m).
// ---------------------------------------------------------------------------
__global__ __launch_bounds__(128) void k_q(const float* __restrict__ slots,
                                           const float* __restrict__ lnw, const float* __restrict__ lnb,
                                           const float* __restrict__ Wq, float* __restrict__ q) {
    __shared__ float xs[128];
    __shared__ float red[4];
    const int t = threadIdx.x;
    const int bm = blockIdx.x;
    float x = slots[bm * 128 + t];
    float s = x, s2 = x * x;
#pragma unroll
    for (int off = 32; off > 0; off >>= 1) { s += __shfl_xor(s, off); s2 += __shfl_xor(s2, off); }
    const int wid = t >> 6, lane = t & 63;
    if (lane == 0) { red[wid * 2] = s; red[wid * 2 + 1] = s2; }
    __syncthreads();
    float S1 = red[0] + red[2], S2 = red[1] + red[3];
    float m = S1 * (1.f / 128.f);
    float rstd = rsqrtf(S2 * (1.f / 128.f) - m * m + LN_EPS_F);
    xs[t] = (x - m) * rstd * lnw[t] + lnb[t];
    __syncthreads();
    const float* wr = Wq + (size_t)t * 128;
    float acc = 0.f;
#pragma unroll 8
    for (int d = 0; d < 128; d += 4) {
        float4 w = *reinterpret_cast<const float4*>(wr + d);
        acc += w.x * xs[d] + w.y * xs[d + 1] + w.z * xs[d + 2] + w.w * xs[d + 3];
    }
    q[bm * 128 + t] = acc * 0.08838834764831845f;
}

// ---------------------------------------------------------------------------
// Kernel 4: fused attn logits + softmax + partial updates per (b,chunk).
// ---------------------------------------------------------------------------
__global__ __launch_bounds__(256) void k_attnupd(const u16* __restrict__ kv, const float* __restrict__ q,
                                                 float* __restrict__ upd_part, float* __restrict__ colsum_part) {
    __shared__ float qs[8 * 128];
    __shared__ float at[128][8];
    __shared__ __bf16 vt[128][128];
    __shared__ float colpart[4][8];
    const int b  = blockIdx.y;
    const int ch = blockIdx.x;
    const int t  = threadIdx.x;
    const int lane = t & 63, wv = t >> 6;
    *reinterpret_cast<float4*>(&qs[t * 4]) = *reinterpret_cast<const float4*>(&q[b * 1024 + t * 4]);
    __syncthreads();
    {
        const int rsub = lane >> 4;
        const int csub = (lane & 15) * 8;
#pragma unroll
        for (int p = 0; p < 8; ++p) {
            int row = wv * 32 + p * 4;
            const u16* src = kv + ((size_t)(b * Nn + ch * 128 + row + rsub)) * 256 + 128 + csub;
            load_lds16(src, &vt[row][0]);
        }
    }
    const int nl   = t >> 1;
    const int half = t & 1;
    const u16* krow = kv + ((size_t)(b * Nn + ch * 128 + nl)) * 256 + half * 64;
    float acc[8] = {0.f, 0.f, 0.f, 0.f, 0.f, 0.f, 0.f, 0.f};
#pragma unroll
    for (int c = 0; c < 8; ++c) {
        v8bf kvv = *reinterpret_cast<const v8bf*>(krow + c * 8);
        float kf[8];
#pragma unroll
        for (int j = 0; j < 8; ++j) kf[j] = (float)kvv[j];
#pragma unroll
        for (int m = 0; m < 8; ++m) {
            const float* qrow = &qs[m * 128 + half * 64 + c * 8];
            float aa = 0.f;
#pragma unroll
            for (int j = 0; j < 8; ++j) aa += kf[j] * qrow[j];
            acc[m] += aa;
        }
    }
#pragma unroll
    for (int m = 0; m < 8; ++m) acc[m] += __shfl_xor(acc[m], 1);
    float mx = acc[0];
#pragma unroll
    for (int m = 1; m < 8; ++m) mx = fmaxf(mx, acc[m]);
    float e[8]; float ssum = 0.f;
#pragma unroll
    for (int m = 0; m < 8; ++m) { e[m] = __expf(acc[m] - mx); ssum += e[m]; }
    float inv = 1.0f / ssum;
    float a8[8];
#pragma unroll
    for (int m = 0; m < 8; ++m) a8[m] = e[m] * inv + ATTN_EPS;
    *reinterpret_cast<float4*>(&at[nl][half * 4]) =
        make_float4(a8[half * 4], a8[half * 4 + 1], a8[half * 4 + 2], a8[half * 4 + 3]);
#pragma unroll
    for (int m = 0; m < 8; ++m) {
        float v = a8[m];
#pragma unroll
        for (int off = 32; off > 0; off >>= 1) v += __shfl_xor(v, off);
        if (lane == 0) colpart[wv][m] = v * 0.5f;
    }
    __syncthreads();
    const int m2 = t >> 5;
    const int s0 = (t & 31) * 4;
    float a0 = 0.f, a1 = 0.f, a2 = 0.f, a3 = 0.f;
#pragma unroll 4
    for (int n = 0; n < 128; ++n) {
        float a = at[n][m2];
        v4bf vvv = *reinterpret_cast<const v4bf*>(&vt[n][s0]);
        a0 += a * (float)vvv[0];
        a1 += a * (float)vvv[1];
        a2 += a * (float)vvv[2];
        a3 += a * (float)vvv[3];
    }
    *reinterpret_cast<float4*>(upd_part + ((size_t)(b * 32 + ch) * 8 + m2) * 128 + s0) =
        make_float4(a0, a1, a2, a3);
    if (t < 8)
        colsum_part[(b * 32 + ch) * 8 + t] =
            colpart[0][t] + colpart[1][t] + colpart[2][t] + colpart[3][t];
}

// ---------------------------------------------------------------------------
// Kernel 5: reduce partials, GRU, LN, MLP -> new slots; next-iter q.
// 256 threads: (tid, half) split-K halves the serial fma chains; 4 waves.
// ---------------------------------------------------------------------------
__global__ __launch_bounds__(256) void k_finishq(const float* __restrict__ upd_part,
                                                 const float* __restrict__ colsum_part,
                                                 const float* __restrict__ slots_in,
                                                 const float* __restrict__ Wih, const float* __restrict__ Whh,
                                                 const float* __restrict__ bih, const float* __restrict__ bhh,
                                                 const float* __restrict__ lnw, const float* __restrict__ lnb,
                                                 const float* __restrict__ W1, const float* __restrict__ b1,
                                                 const float* __restrict__ W2, const float* __restrict__ b2,
                                                 const float* __restrict__ lnsw, const float* __restrict__ lnsb,
                                                 const float* __restrict__ Wq,
                                                 float* __restrict__ slots_out, float* __restrict__ qout) {
    __shared__ float us[128], sp[128], hnorm[128], qsrc[128], act[256];
    __shared__ float upart[2][128];
    __shared__ float gpart[2][6][128];
    __shared__ float p2[2][128];
    __shared__ float qpart[2][128];
    __shared__ float red[4];
    __shared__ float csum_sh;
    const int t   = threadIdx.x;
    const int tid = t & 127, half = t >> 7;
    const int bm  = blockIdx.x;
    const int b = bm >> 3, m = bm & 7;
    if (t < 64) {
        float v = (t < 32) ? colsum_part[(b * 32 + t) * 8 + m] : 0.f;
#pragma unroll
        for (int off = 32; off > 0; off >>= 1) v += __shfl_xor(v, off);
        if (t == 0) csum_sh = v;
    }
    float u = 0.f;
#pragma unroll 4
    for (int chk = half * 16; chk < half * 16 + 16; ++chk)
        u += upd_part[((size_t)(b * 32 + chk) * 8 + m) * 128 + tid];
    upart[half][tid] = u;
    if (half == 0) sp[tid] = slots_in[bm * 128 + tid];
    __syncthreads();
    if (half == 0) us[tid] = (upart[0][tid] + upart[1][tid]) * (1.f / csum_sh);
    __syncthreads();
    // ---- GRU partial dots (split-K over halves)
    {
        const int d0g = half * 64;
        float a_r = 0.f, a_z = 0.f, a_n = 0.f, b_r = 0.f, b_z = 0.f, b_n = 0.f;
        const float* Wr = Wih + (size_t)tid * 128 + d0g;
        const float* Wz = Wih + (size_t)(128 + tid) * 128 + d0g;
        const float* Wn = Wih + (size_t)(256 + tid) * 128 + d0g;
        const float* Vr = Whh + (size_t)tid * 128 + d0g;
        const float* Vz = Whh + (size_t)(128 + tid) * 128 + d0g;
        const float* Vn = Whh + (size_t)(256 + tid) * 128 + d0g;
#pragma unroll 4
        for (int d = 0; d < 64; d += 4) {
            float u0 = us[d0g + d], u1 = us[d0g + d + 1], u2 = us[d0g + d + 2], u3 = us[d0g + d + 3];
            float p0 = sp[d0g + d], p1 = sp[d0g + d + 1], p2_ = sp[d0g + d + 2], p3 = sp[d0g + d + 3];
            float4 w;
            w = *reinterpret_cast<const float4*>(Wr + d); a_r += w.x*u0 + w.y*u1 + w.z*u2 + w.w*u3;
            w = *reinterpret_cast<const float4*>(Wz + d); a_z += w.x*u0 + w.y*u1 + w.z*u2 + w.w*u3;
            w = *reinterpret_cast<const float4*>(Wn + d); a_n += w.x*u0 + w.y*u1 + w.z*u2 + w.w*u3;
            w = *reinterpret_cast<const float4*>(Vr + d); b_r += w.x*p0 + w.y*p1 + w.z*p2_ + w.w*p3;
            w = *reinterpret_cast<const float4*>(Vz + d); b_z += w.x*p0 + w.y*p1 + w.z*p2_ + w.w*p3;
            w = *reinterpret_cast<const float4*>(Vn + d); b_n += w.x*p0 + w.y*p1 + w.z*p2_ + w.w*p3;
        }
        gpart[half][0][tid] = a_r; gpart[half][1][tid] = a_z; gpart[half][2][tid] = a_n;
        gpart[half][3][tid] = b_r; gpart[half][4][tid] = b_z; gpart[half][5][tid] = b_n;
    }
    __syncthreads();
    float gir = bih[tid]       + gpart[0][0][tid] + gpart[1][0][tid];
    float giz = bih[128 + tid] + gpart[0][1][tid] + gpart[1][1][tid];
    float gin = bih[256 + tid] + gpart[0][2][tid] + gpart[1][2][tid];
    float ghr = bhh[tid]       + gpart[0][3][tid] + gpart[1][3][tid];
    float ghz = bhh[128 + tid] + gpart[0][4][tid] + gpart[1][4][tid];
    float ghn = bhh[256 + tid] + gpart[0][5][tid] + gpart[1][5][tid];
    float h0 = sp[tid];
    float r  = 1.f / (1.f + __expf(-(gir + ghr)));
    float z  = 1.f / (1.f + __expf(-(giz + ghz)));
    float nn = tanhf(gin + r * ghn);
    float h  = (1.f - z) * nn + z * h0;
    // ---- LN(h) (reduce on half 0: waves 0-1)
    if (half == 0) {
        float s = h, s2 = h * h;
#pragma unroll
        for (int off = 32; off > 0; off >>= 1) { s += __shfl_xor(s, off); s2 += __shfl_xor(s2, off); }
        if ((t & 63) == 0) { red[(tid >> 6) * 2] = s; red[(tid >> 6) * 2 + 1] = s2; }
    }
    __syncthreads();
    {
        float S1 = red[0] + red[2], S2 = red[1] + red[3];
        float mean = S1 * (1.f / Ss);
        float rstd = rsqrtf(S2 * (1.f / Ss) - mean * mean + LN_EPS_F);
        if (half == 0) hnorm[tid] = (h - mean) * rstd * lnw[tid] + lnb[tid];
    }
    __syncthreads();
    // ---- MLP1: each of 256 threads one output
    {
        float a = b1[t];
        const float* w1r = W1 + (size_t)t * 128;
#pragma unroll 4
        for (int d = 0; d < 128; d += 4) {
            float4 w = *reinterpret_cast<const float4*>(w1r + d);
            a += w.x * hnorm[d] + w.y * hnorm[d + 1] + w.z * hnorm[d + 2] + w.w * hnorm[d + 3];
        }
        act[t] = fmaxf(a, 0.f);
    }
    __syncthreads();
    // ---- MLP2 split-K
    {
        float o = 0.f;
        const int j0 = half * 128;
        const float* w2r = W2 + (size_t)tid * 256 + j0;
#pragma unroll 4
        for (int j = 0; j < 128; j += 4) {
            float4 w = *reinterpret_cast<const float4*>(w2r + j);
            o += w.x * act[j0 + j] + w.y * act[j0 + j + 1] + w.z * act[j0 + j + 2] + w.w * act[j0 + j + 3];
        }
        p2[half][tid] = o;
    }
    __syncthreads();
    float snew = h + b2[tid] + p2[0][tid] + p2[1][tid];
    if (half == 0) slots_out[bm * 128 + tid] = snew;
    // ---- next-iter q
    if (half == 0) {
        float s = snew, s2 = snew * snew;
#pragma unroll
        for (int off = 32; off > 0; off >>= 1) { s += __shfl_xor(s, off); s2 += __shfl_xor(s2, off); }
        if ((t & 63) == 0) { red[(tid >> 6) * 2] = s; red[(tid >> 6) * 2 + 1] = s2; }
    }
    __syncthreads();
    {
        float T1 = red[0] + red[2], T2 = red[1] + red[3];
        float m2 = T1 * (1.f / Ss);
        float rstd2 = rsqrtf(T2 * (1.f / Ss) - m2 * m2 + LN_EPS_F);
        if (half == 0) qsrc[tid] = (snew - m2) * rstd2 * lnsw[tid] + lnsb[tid];
    }
    __syncthreads();
    {
        float qa = 0.f;
        const int d0g = half * 64;
        const float* wr = Wq + (size_t)tid * 128 + d0g;
#pragma unroll 4
        for (int d = 0; d < 64; d += 4) {
            float4 w = *reinterpret_cast<const float4*>(wr + d);
            qa += w.x * qsrc[d0g + d] + w.y * qsrc[d0g + d + 1] + w.z * qsrc[d0g + d + 2] + w.w * qsrc[d0g + d + 3];
        }
        qpart[half][tid] = qa;
    }
    __syncthreads();
    if (half == 0)
        qout[bm * 128 + tid] = (qpart[0][tid] + qpart[1][tid]) * 0.08838834764831845f;
}

// ---------------------------------------------------------------------------
extern "C" void kernel_launch(void* const* d_in, const int* in_sizes, int n_in,
                              void* d_out, int out_size, void* d_ws, size_t ws_size,
                              hipStream_t stream) {
    const float* X          = (const float*)d_in[0];
    const float* slots_init = (const float*)d_in[1];
    const float* ln_in_w    = (const float*)d_in[2];
    const float* ln_in_b    = (const float*)d_in[3];
    const float* ln_slot_w  = (const float*)d_in[4];
    const float* ln_slot_b  = (const float*)d_in[5];
    const float* ln_mlp_w   = (const float*)d_in[6];
    const float* ln_mlp_b   = (const float*)d_in[7];
    const float* Wq         = (const float*)d_in[8];
    const float* Wk         = (const float*)d_in[9];
    const float* Wv         = (const float*)d_in[10];
    const float* gWih       = (const float*)d_in[11];
    const float* gWhh       = (const float*)d_in[12];
    const float* gbih       = (const float*)d_in[13];
    const float* gbhh       = (const float*)d_in[14];
    const float* W1         = (const float*)d_in[15];
    const float* b1         = (const float*)d_in[16];
    const float* W2         = (const float*)d_in[17];
    const float* b2         = (const float*)d_in[18];
    const float* mu         = (const float*)d_in[19];
    const float* lsig       = (const float*)d_in[20];

    char* p = (char*)d_ws;
    u16*    Wkvp        = (u16*)p;    p += (size_t)256 * 512 * sizeof(u16);           // 256 KB
    float*  cb          = (float*)p;  p += 256 * sizeof(float);
    float*  Scol        = (float*)p;  p += 256 * sizeof(float);
    float*  slots       = (float*)p;  p += 32 * 8 * 128 * sizeof(float);              // 128 KB
    float*  qbuf        = (float*)p;  p += 32 * 8 * 128 * sizeof(float);              // 128 KB
    float*  colsum_part = (float*)p;  p += 32 * 32 * 8 * sizeof(float);               // 32 KB
    float*  upd_part    = (float*)p;  p += (size_t)32 * 32 * 8 * 128 * sizeof(float); // 4 MB
    u16*    kv          = (u16*)p;    p += (size_t)MROWS * 256 * sizeof(u16);         // 67 MB

    k_prep<<<648, 256, 0, stream>>>(Wk, Wv, ln_in_w, ln_in_b, slots_init, mu, lsig,
                                    Wkvp, cb, Scol, slots);
    k_kvgemm<<<MROWS / 64, 256, 0, stream>>>(X, Wkvp, cb, Scol, kv);
    k_q<<<256, 128, 0, stream>>>(slots, ln_slot_w, ln_slot_b, Wq, qbuf);

    for (int it = 0; it < 3; ++it) {
        k_attnupd<<<dim3(32, 32), 256, 0, stream>>>(kv, qbuf, upd_part, colsum_part);
        k_finishq<<<256, 256, 0, stream>>>(upd_part, colsum_part, slots,
                                           gWih, gWhh, gbih, gbhh,
                                           ln_mlp_w, ln_mlp_b, W1, b1, W2, b2,
                                           ln_slot_w, ln_slot_b, Wq,
                                           (it == 2) ? (float*)d_out : slots, qbuf);
    }
}